// Round 18
// baseline (251.508 us; speedup 1.0000x reference)
//
#include <hip/hip_runtime.h>

#define NEG_INF -1e10f
#define B_   8
#define LQ_  2048
#define LK_  2048
#define D_   1024

typedef unsigned int uint;
typedef unsigned short u16;
typedef _Float16 f16;
typedef _Float16 f16x8_t __attribute__((ext_vector_type(8)));
typedef float f32x4_t __attribute__((ext_vector_type(4)));
typedef float f32x4v __attribute__((ext_vector_type(4)));    // for nontemporal
typedef unsigned short u16x4v __attribute__((ext_vector_type(4)));

// ---------- helpers ----------
__device__ __forceinline__ u16 f2h_bits(float f) {
    f16 h = (f16)f;
    return __builtin_bit_cast(u16, h);
}
__device__ __forceinline__ void gload_lds16(const void* g, void* l) {
    __builtin_amdgcn_global_load_lds(
        (const __attribute__((address_space(1))) uint*)g,
        (__attribute__((address_space(3))) uint*)l, 16, 0, 0);
}

// ---------- fused fp32 -> fp16 for two tensors (K and Q) ----------
__global__ __launch_bounds__(256) void convert_f16_2(
    const float4* __restrict__ s1, ushort4* __restrict__ d1,
    const float4* __restrict__ s2, ushort4* __restrict__ d2, int n4)
{
    int idx = blockIdx.x * 256 + threadIdx.x;
    const int stride = gridDim.x * 256;
    for (; idx < 2 * n4; idx += stride) {
        const bool second = idx >= n4;
        const int i = second ? idx - n4 : idx;
        float4 x = second ? s2[i] : s1[i];
        ushort4 h;
        h.x = f2h_bits(x.x);
        h.y = f2h_bits(x.y);
        h.z = f2h_bits(x.z);
        h.w = f2h_bits(x.w);
        if (second) d2[i] = h; else d1[i] = h;
    }
}

// ---------- V [z][2048][1024] fp32 -> VT [z][1024][2048] fp16 ----------
__global__ __launch_bounds__(256) void transpose_convert(
    const float* __restrict__ V, u16* __restrict__ VT)
{
    __shared__ float tile[64][65];
    const int t  = threadIdx.x;
    const int d0 = blockIdx.x * 64;
    const int k0 = blockIdx.y * 64;
    const float* Vb = V + (size_t)blockIdx.z * (LK_ * D_);
    u16* VTb = VT + (size_t)blockIdx.z * (D_ * LK_);
#pragma unroll
    for (int i = 0; i < 4; ++i) {
        int f = i * 256 + t;
        int r = f >> 4, c4 = f & 15;
        float4 v = *(const float4*)&Vb[(size_t)(k0 + r) * D_ + d0 + c4 * 4];
        tile[r][c4 * 4 + 0] = v.x;
        tile[r][c4 * 4 + 1] = v.y;
        tile[r][c4 * 4 + 2] = v.z;
        tile[r][c4 * 4 + 3] = v.w;
    }
    __syncthreads();
#pragma unroll
    for (int i = 0; i < 4; ++i) {
        int f = i * 256 + t;
        int d = f >> 4, c4 = f & 15;
        ushort4 o;
        o.x = f2h_bits(tile[c4 * 4 + 0][d]);
        o.y = f2h_bits(tile[c4 * 4 + 1][d]);
        o.z = f2h_bits(tile[c4 * 4 + 2][d]);
        o.w = f2h_bits(tile[c4 * 4 + 3][d]);
        *(ushort4*)&VTb[(size_t)(d0 + d) * LK_ + k0 + c4 * 4] = o;
    }
}

// ===================================================================
// 8-phase counted-vmcnt GEMM (R11-R16-verified schedule), 256x256 tile,
// ring-4 (128 KiB).
//  QK: <NTILES=32, SPLIT=false, GRID=0>  straight K=1024, 8x8 grid
//      (64 blocks/batch), XCD owns 2m x 4n.
//  PV: <NTILES=64, SPLIT=true,  GRID=1>  virtual K=2048 via A-pointer
//      switch (P rows in S), 8m x 4n grid (32 blocks), XCD owns 2x2.
//  R18 (=R17 retry): C-writes are NONTEMPORAL — bypass L2 allocation
//  so the 131/65 MB store stream stops evicting staged operand panels
//  (R15 FETCH showed 1.5x over-fetch) and drains at write BW.
// ===================================================================
#define BM_  256
#define BK_  32

template<int NTILES, bool SPLIT, int GRID>
__global__ __launch_bounds__(512, 2) void gemm8p(
    const u16* __restrict__ A0g, const u16* __restrict__ A1g,
    const u16* __restrict__ Bg, float* __restrict__ Cg,
    int lda, int ldb, int ldc, int bkmask,
    size_t szA, size_t szB, size_t szC)
{
    constexpr int NBF    = 4;
    constexpr int BN     = 64 * NBF;
    constexpr int ABYTES = BM_ * BK_ * 2;          // 16384
    constexpr int BBYTES = BN * BK_ * 2;           // 16384
    constexpr int BUFSZ  = ABYTES + BBYTES;        // 32768
    __shared__ char lds[4 * BUFSZ];

    const int tid  = threadIdx.x;
    const int lane = tid & 63;
    const int w    = tid >> 6;           // 0..7
    const int wm   = w >> 2;             // 0..1
    const int wn   = w & 3;              // 0..3

    // ---- T1 XCD rectangle remap ----
    const int d  = blockIdx.x;
    const int g  = d & 7;                // xcd (heuristic: bid % 8)
    const int k_ = d >> 3;
    int m0, n0;
    if constexpr (GRID == 0) {           // QK: 8x8 grid, XCD 2m x 4n
        m0 = ((g >> 1) * 2 + (k_ & 1)) * 256;
        n0 = ((g & 1) * 4 + (k_ >> 1)) * 256;
    } else {                             // PV: 8m x 4n grid, XCD 2x2
        m0 = ((g >> 1) * 2 + (k_ & 1)) * 256;
        n0 = ((g & 1) * 2 + (k_ >> 1)) * 256;
    }
    const size_t z = blockIdx.y;

    const u16* A0 = A0g + z * szA;
    const u16* A1 = A1g + z * szA;
    const u16* B  = Bg  + z * szB;
    float* C = Cg + z * szC;

    const int  lr   = lane & 15;
    // T2 swizzle (R7-verified, conflicts=0): chunk' = chunk ^ ((row>>1)&3)
    const uint csel = (uint)((((lane >> 4) ^ ((lane >> 1) & 3)) * 16));
    const int  cstg = (((lane & 3) ^ ((lane >> 3) & 3)) * 8);
    const int  rstg = lane >> 2;

    const uint awoff = (uint)(wm * 8192 + lr * 64) + csel;
    const uint bwoff = (uint)(wn * (NBF * 1024) + lr * 64) + csel;

    f32x4_t acc[8][NBF];
#pragma unroll
    for (int m = 0; m < 8; ++m)
#pragma unroll
        for (int n = 0; n < NBF; ++n)
            acc[m][n] = (f32x4_t){0.f, 0.f, 0.f, 0.f};

    auto stA = [&](int t) {
        const u16* Ab;
        int kc;
        if constexpr (SPLIT) {
            Ab = (t < NTILES / 2) ? A0 : A1;
            kc = (t & (NTILES / 2 - 1)) * BK_ + cstg;
        } else {
            Ab = A0;
            kc = t * BK_ + cstg;
        }
        char* dst = lds + (t & 3) * BUFSZ + w * 2048;
        gload_lds16(&Ab[(size_t)(m0 + w * 32 + rstg) * lda + kc], dst);
        gload_lds16(&Ab[(size_t)(m0 + w * 32 + 16 + rstg) * lda + kc], dst + 1024);
    };
    auto stB = [&](int t) {
        const int kc = ((t * BK_) & bkmask) + cstg;
        char* dst = lds + (t & 3) * BUFSZ + ABYTES;
        gload_lds16(&B[(size_t)(n0 + w * 32 + rstg) * ldb + kc], dst + w * 2048);
        gload_lds16(&B[(size_t)(n0 + w * 32 + 16 + rstg) * ldb + kc], dst + w * 2048 + 1024);
    };

    stA(0); stB(0); stA(1); stB(1); stA(2); stB(2);
    asm volatile("s_waitcnt vmcnt(8)" ::: "memory");
    __builtin_amdgcn_s_barrier();

#define LDF(p) (*(const f16x8_t*)(p))

#define PHASE_A(T, DOSTAGE)                                                   \
    {                                                                         \
        const char* pA = lds + ((T) & 3) * BUFSZ + awoff;                     \
        const char* pB = lds + ((T) & 3) * BUFSZ + ABYTES + bwoff;            \
        f16x8_t a[4], b[NBF];                                                 \
        a[0] = LDF(pA);        a[1] = LDF(pA + 1024);                         \
        a[2] = LDF(pA + 2048); a[3] = LDF(pA + 3072);                         \
        b[0] = LDF(pB);        b[1] = LDF(pB + 1024);                         \
        b[2] = LDF(pB + 2048); b[3] = LDF(pB + 3072);                         \
        if (DOSTAGE) stA((T) + 3);                                            \
        __builtin_amdgcn_s_barrier();                                         \
        __builtin_amdgcn_s_setprio(1);                                        \
        _Pragma("unroll")                                                     \
        for (int mf = 0; mf < 4; ++mf)                                        \
            _Pragma("unroll")                                                 \
            for (int nf = 0; nf < NBF; ++nf)                                  \
                acc[mf][nf] = __builtin_amdgcn_mfma_f32_16x16x32_f16(         \
                    a[mf], b[nf], acc[mf][nf], 0, 0, 0);                      \
        __builtin_amdgcn_s_setprio(0);                                        \
        bsave[0] = b[0]; bsave[1] = b[1]; bsave[2] = b[2]; bsave[3] = b[3];   \
        __builtin_amdgcn_s_barrier();                                         \
    }

#define PHASE_B(T, DOSTAGE, VMASM)                                            \
    {                                                                         \
        const char* pA = lds + ((T) & 3) * BUFSZ + awoff;                     \
        f16x8_t a[4];                                                         \
        a[0] = LDF(pA + 4096); a[1] = LDF(pA + 5120);                         \
        a[2] = LDF(pA + 6144); a[3] = LDF(pA + 7168);                         \
        if (DOSTAGE) stB((T) + 3);                                            \
        __builtin_amdgcn_s_barrier();                                         \
        __builtin_amdgcn_s_setprio(1);                                        \
        _Pragma("unroll")                                                     \
        for (int mf = 0; mf < 4; ++mf)                                        \
            _Pragma("unroll")                                                 \
            for (int nf = 0; nf < NBF; ++nf)                                  \
                acc[4 + mf][nf] = __builtin_amdgcn_mfma_f32_16x16x32_f16(     \
                    a[mf], bsave[nf], acc[4 + mf][nf], 0, 0, 0);              \
        __builtin_amdgcn_s_setprio(0);                                        \
        VMASM;                                                                \
        __builtin_amdgcn_s_barrier();                                         \
    }

#define VMW asm volatile("s_waitcnt vmcnt(8)" ::: "memory")
#define VMH asm volatile("s_waitcnt vmcnt(4)" ::: "memory")
#define VM0 asm volatile("s_waitcnt vmcnt(0)" ::: "memory")
#define VMN do {} while (0)

    f16x8_t bsave[NBF];

    for (int t = 0; t < NTILES - 3; ++t) {
        PHASE_A(t, true);
        PHASE_B(t, true, VMW);
    }
    PHASE_A(NTILES - 3, false); PHASE_B(NTILES - 3, false, VMH);
    PHASE_A(NTILES - 2, false); PHASE_B(NTILES - 2, false, VM0);
    PHASE_A(NTILES - 1, false); PHASE_B(NTILES - 1, false, VMN);
#undef PHASE_A
#undef PHASE_B
#undef LDF

    // ---- epilogue: NONTEMPORAL C write (fp32, nt flag: no L2 alloc) ----
    const int cg = lane >> 4;
#pragma unroll
    for (int mf = 0; mf < 8; ++mf)
#pragma unroll
        for (int nf = 0; nf < NBF; ++nf) {
            const int row = m0 + wm * 128 + mf * 16 + cg * 4;
            const int col = n0 + wn * (NBF * 16) + nf * 16 + lr;
#pragma unroll
            for (int r = 0; r < 4; ++r)
                __builtin_nontemporal_store(
                    acc[mf][nf][r], &C[(size_t)(row + r) * ldc + col]);
        }
}

// ---------- masked row softmax, z-batched: S fp32 -> P fp16 IN PLACE ----------
// Nontemporal S-read (streamed once) and P-write (evicted before PV anyway).
// Uses clang ext_vector types (HIP_vector_type rejected by the builtin).
__global__ __launch_bounds__(256) void softmax_mask(
    float* __restrict__ S, const int* __restrict__ mask0)
{
    const int lane = threadIdx.x & 63;
    const int wave = threadIdx.x >> 6;
    const int row  = blockIdx.x * 4 + wave;
    const size_t zb = blockIdx.y;
    float* Sr = S + (zb * LQ_ + row) * (size_t)LK_;
    const int* mb = mask0 + zb * LK_;

    f32x4v s[8];
    float m = -INFINITY;
#pragma unroll
    for (int i = 0; i < 8; ++i) {
        int k = i * 256 + lane * 4;
        f32x4v v = __builtin_nontemporal_load((const f32x4v*)&Sr[k]);
        int4 mk  = *(const int4*)&mb[k];
        v.x = mk.x ? v.x : NEG_INF;
        v.y = mk.y ? v.y : NEG_INF;
        v.z = mk.z ? v.z : NEG_INF;
        v.w = mk.w ? v.w : NEG_INF;
        s[i] = v;
        m = fmaxf(m, fmaxf(fmaxf(v.x, v.y), fmaxf(v.z, v.w)));
    }
#pragma unroll
    for (int off = 32; off > 0; off >>= 1)
        m = fmaxf(m, __shfl_xor(m, off, 64));
    float sum = 0.f;
#pragma unroll
    for (int i = 0; i < 8; ++i) {
        s[i].x = __expf(s[i].x - m); sum += s[i].x;
        s[i].y = __expf(s[i].y - m); sum += s[i].y;
        s[i].z = __expf(s[i].z - m); sum += s[i].z;
        s[i].w = __expf(s[i].w - m); sum += s[i].w;
    }
#pragma unroll
    for (int off = 32; off > 0; off >>= 1)
        sum += __shfl_xor(sum, off, 64);
    const float inv = 1.f / sum;
    u16* Pr = (u16*)Sr;
#pragma unroll
    for (int i = 0; i < 8; ++i) {
        int k = i * 256 + lane * 4;
        u16x4v o;
        o.x = f2h_bits(s[i].x * inv);
        o.y = f2h_bits(s[i].y * inv);
        o.z = f2h_bits(s[i].z * inv);
        o.w = f2h_bits(s[i].w * inv);
        __builtin_nontemporal_store(o, (u16x4v*)&Pr[k]);
    }
}

// ---------- fallback (verified R1 fp32 kernel) ----------
__global__ __launch_bounds__(256, 2) void attn_fp32_flash(
    const float* __restrict__ hidden, const float* __restrict__ keys,
    const float* __restrict__ values, const int* __restrict__ mask,
    float* __restrict__ out)
{
    const int lane = threadIdx.x & 63;
    const int wave = threadIdx.x >> 6;
    const int blk  = blockIdx.x;
    const int b    = blk >> 7;
    const int q0   = (blk & 127) * 16 + wave * 4;
    float4 q[4][4]; float4 o[4][4]; float m[4], s[4];
    const float4* hp = (const float4*)(hidden + ((size_t)b * LQ_ + q0) * D_);
#pragma unroll
    for (int r = 0; r < 4; ++r) {
#pragma unroll
        for (int j = 0; j < 4; ++j) {
            q[r][j] = hp[r * 256 + j * 64 + lane];
            o[r][j] = make_float4(0.f, 0.f, 0.f, 0.f);
        }
        m[r] = -INFINITY; s[r] = 0.f;
    }
    const float4* kp = (const float4*)(keys   + (size_t)b * LK_ * D_);
    const float4* vp = (const float4*)(values + (size_t)b * LK_ * D_);
    const int*    mp = mask + b * LK_;
    for (int k = 0; k < LK_; ++k) {
        float4 kv[4];
#pragma unroll
        for (int j = 0; j < 4; ++j) kv[j] = kp[k * 256 + j * 64 + lane];
        float sc[4];
#pragma unroll
        for (int r = 0; r < 4; ++r) {
            float p = 0.f;
#pragma unroll
            for (int j = 0; j < 4; ++j)
                p += q[r][j].x * kv[j].x + q[r][j].y * kv[j].y +
                     q[r][j].z * kv[j].z + q[r][j].w * kv[j].w;
            sc[r] = p;
        }
#pragma unroll
        for (int r = 0; r < 4; ++r)
#pragma unroll
            for (int off = 32; off > 0; off >>= 1)
                sc[r] += __shfl_xor(sc[r], off, 64);
        const int mk = mp[k];
        float4 vv[4];
#pragma unroll
        for (int j = 0; j < 4; ++j) vv[j] = vp[k * 256 + j * 64 + lane];
#pragma unroll
        for (int r = 0; r < 4; ++r) {
            float score = mk ? sc[r] : NEG_INF;
            if (score > m[r]) {
                float scale = __expf(m[r] - score);
                m[r] = score; s[r] *= scale;
#pragma unroll
                for (int j = 0; j < 4; ++j) {
                    o[r][j].x *= scale; o[r][j].y *= scale;
                    o[r][j].z *= scale; o[r][j].w *= scale;
                }
            }
            float e = __expf(score - m[r]);
            s[r] += e;
#pragma unroll
            for (int j = 0; j < 4; ++j) {
                o[r][j].x += e * vv[j].x; o[r][j].y += e * vv[j].y;
                o[r][j].z += e * vv[j].z; o[r][j].w += e * vv[j].w;
            }
        }
    }
    float4* op = (float4*)(out + ((size_t)b * LQ_ + q0) * D_);
#pragma unroll
    for (int r = 0; r < 4; ++r) {
        float inv = 1.f / s[r];
#pragma unroll
        for (int j = 0; j < 4; ++j) {
            float4 t = o[r][j];
            t.x *= inv; t.y *= inv; t.z *= inv; t.w *= inv;
            op[r * 256 + j * 64 + lane] = t;
        }
    }
}

extern "C" void kernel_launch(void* const* d_in, const int* in_sizes, int n_in,
                              void* d_out, int out_size, void* d_ws, size_t ws_size,
                              hipStream_t stream) {
    const float* hidden = (const float*)d_in[0];
    const float* keys   = (const float*)d_in[1];
    const float* values = (const float*)d_in[2];
    const int*   mask   = (const int*)d_in[3];
    float* out = (float*)d_out;
    char* ws = (char*)d_ws;

    const size_t TEN = (size_t)LK_ * D_;          // 2M elems per batch tensor
    const size_t MB  = 1024ull * 1024;

    // per-batch footprint: Kh 4 + VT 4 + Qh 4 + S 16 (P in place) = 28 MiB
    int BG = 0;
    for (int g = 8; g >= 1; g >>= 1)
        if ((size_t)g * 28 * MB <= ws_size) { BG = g; break; }

    if (BG == 0) {
        attn_fp32_flash<<<1024, 256, 0, stream>>>(hidden, keys, values, mask, out);
        return;
    }

    const size_t SZ_BF = (size_t)BG * TEN * 2;            // BG*4 MiB per u16 tensor
    u16*   Kh = (u16*)(ws);
    u16*   VT = (u16*)(ws + SZ_BF);
    u16*   Qh = (u16*)(ws + 2 * SZ_BF);
    float* S  = (float*)(ws + 3 * SZ_BF);                 // BG*16 MiB

    const int n4 = BG * (int)(TEN / 4);

    for (int bg0 = 0; bg0 < B_; bg0 += BG) {
        const size_t off = (size_t)bg0 * TEN;
        // K and Q fp16 converts fused into one dispatch
        convert_f16_2<<<4096, 256, 0, stream>>>(
            (const float4*)(keys + off), (ushort4*)Kh,
            (const float4*)(hidden + off), (ushort4*)Qh, n4);
        transpose_convert<<<dim3(16, 32, BG), 256, 0, stream>>>(
            values + off, VT);

        // S = Qh * Kh^T — pure fp16, K=1024, 8x8 grid, nontemporal S-write
        gemm8p<32, false, 0><<<dim3(64, BG), 512, 0, stream>>>(
            Qh, Qh, Kh, S, D_, D_, LK_, 1023,
            TEN, TEN, (size_t)LQ_ * LK_);

        // softmax, P written fp16 in place (nontemporal) over S rows
        softmax_mask<<<dim3(LQ_ / 4, BG), 256, 0, stream>>>(
            S, mask + bg0 * LK_);

        // out = P * VT^T — virtual K=2048 via A1 = P + 1024, nontemporal out
        gemm8p<64, true, 1><<<dim3(32, BG), 512, 0, stream>>>(
            (const u16*)S, (const u16*)S + 1024, VT, out + off,
            2 * LK_, LK_, D_, 2047,
            (size_t)LQ_ * 2 * LK_, TEN, (size_t)LQ_ * D_);
    }
}

// Round 19
// 236.843 us; speedup vs baseline: 1.0619x; 1.0619x over previous
//
#include <hip/hip_runtime.h>

#define NEG_INF -1e10f
#define B_   8
#define LQ_  2048
#define LK_  2048
#define D_   1024

typedef unsigned int uint;
typedef unsigned short u16;
typedef _Float16 f16;
typedef _Float16 f16x8_t __attribute__((ext_vector_type(8)));
typedef float f32x4_t __attribute__((ext_vector_type(4)));

// ---------- helpers ----------
__device__ __forceinline__ u16 f2h_bits(float f) {
    f16 h = (f16)f;
    return __builtin_bit_cast(u16, h);
}
__device__ __forceinline__ void gload_lds16(const void* g, void* l) {
    __builtin_amdgcn_global_load_lds(
        (const __attribute__((address_space(1))) uint*)g,
        (__attribute__((address_space(3))) uint*)l, 16, 0, 0);
}

// ---------- fused fp32 -> fp16 for two tensors (K and Q) ----------
__global__ __launch_bounds__(256) void convert_f16_2(
    const float4* __restrict__ s1, ushort4* __restrict__ d1,
    const float4* __restrict__ s2, ushort4* __restrict__ d2, int n4)
{
    int idx = blockIdx.x * 256 + threadIdx.x;
    const int stride = gridDim.x * 256;
    for (; idx < 2 * n4; idx += stride) {
        const bool second = idx >= n4;
        const int i = second ? idx - n4 : idx;
        float4 x = second ? s2[i] : s1[i];
        ushort4 h;
        h.x = f2h_bits(x.x);
        h.y = f2h_bits(x.y);
        h.z = f2h_bits(x.z);
        h.w = f2h_bits(x.w);
        if (second) d2[i] = h; else d1[i] = h;
    }
}

// ---------- V [z][2048][1024] fp32 -> VT [z][1024][2048] fp16 ----------
__global__ __launch_bounds__(256) void transpose_convert(
    const float* __restrict__ V, u16* __restrict__ VT)
{
    __shared__ float tile[64][65];
    const int t  = threadIdx.x;
    const int d0 = blockIdx.x * 64;
    const int k0 = blockIdx.y * 64;
    const float* Vb = V + (size_t)blockIdx.z * (LK_ * D_);
    u16* VTb = VT + (size_t)blockIdx.z * (D_ * LK_);
#pragma unroll
    for (int i = 0; i < 4; ++i) {
        int f = i * 256 + t;
        int r = f >> 4, c4 = f & 15;
        float4 v = *(const float4*)&Vb[(size_t)(k0 + r) * D_ + d0 + c4 * 4];
        tile[r][c4 * 4 + 0] = v.x;
        tile[r][c4 * 4 + 1] = v.y;
        tile[r][c4 * 4 + 2] = v.z;
        tile[r][c4 * 4 + 3] = v.w;
    }
    __syncthreads();
#pragma unroll
    for (int i = 0; i < 4; ++i) {
        int f = i * 256 + t;
        int d = f >> 4, c4 = f & 15;
        ushort4 o;
        o.x = f2h_bits(tile[c4 * 4 + 0][d]);
        o.y = f2h_bits(tile[c4 * 4 + 1][d]);
        o.z = f2h_bits(tile[c4 * 4 + 2][d]);
        o.w = f2h_bits(tile[c4 * 4 + 3][d]);
        *(ushort4*)&VTb[(size_t)(d0 + d) * LK_ + k0 + c4 * 4] = o;
    }
}

#define DSR(dst, base, off) \
    asm volatile("ds_read_b128 %0, %1 offset:" off : "=v"(dst) : "v"(base))

// ===================================================================
// gemm_qk2: S = Qh * Kh^T, K=1024 (32 tiles of BK=32), pure fp16.
// 256x256 tile, 8 waves (2M x 4N), RING-2 LDS (64 KiB -> 2 blocks/CU).
// R10-verified single-barrier ring-2 protocol; launch_bounds(512,2)
// (no acc spill).  Per tile t: vmcnt(0); barrier; stage(t+1);
// 12x ds_read from buf[t&1]; lgkmcnt(4) -> 16 MFMA mh0;
// lgkmcnt(0) -> 16 MFMA mh1.
// ===================================================================
__global__ __launch_bounds__(512, 2) void gemm_qk2(
    const u16* __restrict__ Ag, const u16* __restrict__ Bg,
    float* __restrict__ Cg, size_t szA, size_t szB, size_t szC)
{
    constexpr int NT     = 32;
    constexpr int ABYTES = 256 * 32 * 2;           // 16384
    constexpr int BUFSZ  = 2 * ABYTES;             // 32768 (A + B)
    __shared__ char lds[2 * BUFSZ];                // 64 KiB

    const int tid  = threadIdx.x;
    const int lane = tid & 63;
    const int w    = tid >> 6;
    const int wm   = w >> 2;             // 0..1
    const int wn   = w & 3;              // 0..3

    // T1 XCD 2x4 rectangle remap (8x8 tile grid) — R9-verified
    const int d  = blockIdx.x;
    const int g  = d & 7;
    const int k_ = d >> 3;
    const int m0 = ((g >> 1) * 2 + (k_ & 1)) * 256;
    const int n0 = ((g & 1) * 4 + (k_ >> 1)) * 256;
    const size_t z = blockIdx.y;

    const u16* A = Ag + z * szA;
    const u16* B = Bg + z * szB;
    float* C = Cg + z * szC;

    const uint ldsbase = (uint)(size_t)&lds[0];
    const int  lr   = lane & 15;
    // T2 swizzle (R7-verified, conflicts = 0)
    const uint csel = (uint)((((lane >> 4) ^ ((lane >> 1) & 3)) * 16));
    const int  cstg = (((lane & 3) ^ ((lane >> 3) & 3)) * 8);
    const int  rstg = lane >> 2;

    const uint awoff = (uint)(wm * 8192 + lr * 64) + csel;
    const uint bwoff = (uint)(wn * 4096 + lr * 64) + csel;

    f32x4_t acc[8][4];
#pragma unroll
    for (int m = 0; m < 8; ++m)
#pragma unroll
        for (int n = 0; n < 4; ++n)
            acc[m][n] = (f32x4_t){0.f, 0.f, 0.f, 0.f};

    auto stage = [&](int t) {
        const int kc = t * 32 + cstg;
        char* dA = lds + (t & 1) * BUFSZ + w * 2048;
        char* dB = lds + (t & 1) * BUFSZ + ABYTES + w * 2048;
        gload_lds16(&A[(size_t)(m0 + w * 32 + rstg) * D_ + kc], dA);
        gload_lds16(&A[(size_t)(m0 + w * 32 + 16 + rstg) * D_ + kc], dA + 1024);
        gload_lds16(&B[(size_t)(n0 + w * 32 + rstg) * D_ + kc], dB);
        gload_lds16(&B[(size_t)(n0 + w * 32 + 16 + rstg) * D_ + kc], dB + 1024);
    };

    stage(0);   // prologue

    f16x8_t a0[4], a1[4], b[4];
    for (int t = 0; t < NT; ++t) {
        asm volatile("s_waitcnt vmcnt(0)" ::: "memory");
        __builtin_amdgcn_s_barrier();
        if (t + 1 < NT) stage(t + 1);
        const uint aA = ldsbase + (uint)((t & 1) * BUFSZ) + awoff;
        const uint aB = ldsbase + (uint)((t & 1) * BUFSZ + ABYTES) + bwoff;
        DSR(b[0], aB, "0");     DSR(b[1], aB, "1024");
        DSR(b[2], aB, "2048");  DSR(b[3], aB, "3072");
        DSR(a0[0], aA, "0");    DSR(a0[1], aA, "1024");
        DSR(a0[2], aA, "2048"); DSR(a0[3], aA, "3072");
        DSR(a1[0], aA, "4096"); DSR(a1[1], aA, "5120");
        DSR(a1[2], aA, "6144"); DSR(a1[3], aA, "7168");
        asm volatile("s_waitcnt lgkmcnt(4)");
        __builtin_amdgcn_sched_barrier(0);
        __builtin_amdgcn_s_setprio(1);
#pragma unroll
        for (int mf = 0; mf < 4; ++mf)
#pragma unroll
            for (int nf = 0; nf < 4; ++nf)
                acc[mf][nf] = __builtin_amdgcn_mfma_f32_16x16x32_f16(
                    a0[mf], b[nf], acc[mf][nf], 0, 0, 0);
        asm volatile("s_waitcnt lgkmcnt(0)");
        __builtin_amdgcn_sched_barrier(0);
#pragma unroll
        for (int mf = 0; mf < 4; ++mf)
#pragma unroll
            for (int nf = 0; nf < 4; ++nf)
                acc[4 + mf][nf] = __builtin_amdgcn_mfma_f32_16x16x32_f16(
                    a1[mf], b[nf], acc[4 + mf][nf], 0, 0, 0);
        __builtin_amdgcn_s_setprio(0);
    }

    const int cg = lane >> 4;
#pragma unroll
    for (int mf = 0; mf < 8; ++mf)
#pragma unroll
        for (int nf = 0; nf < 4; ++nf) {
            const int row = m0 + wm * 128 + mf * 16 + cg * 4;
            const int col = n0 + wn * 64 + nf * 16 + lr;
#pragma unroll
            for (int r = 0; r < 4; ++r)
                C[(size_t)(row + r) * LK_ + col] = acc[mf][nf][r];
        }
}

// ===================================================================
// gemm8p (PV): R11-R14-verified 8-phase counted-vmcnt, 256x256 tile,
// ring-4 (128 KiB).  Virtual K=2048 via A-pointer switch (P rows in S).
// ===================================================================
#define BM_  256
#define BK_  32

template<int NTILES>
__global__ __launch_bounds__(512, 2) void gemm8p(
    const u16* __restrict__ A0g, const u16* __restrict__ A1g,
    const u16* __restrict__ Bg, float* __restrict__ Cg,
    int lda, int ldb, int ldc, int bkmask,
    size_t szA, size_t szB, size_t szC)
{
    constexpr int NBF    = 4;
    constexpr int BN     = 64 * NBF;
    constexpr int ABYTES = BM_ * BK_ * 2;          // 16384
    constexpr int BBYTES = BN * BK_ * 2;           // 16384
    constexpr int BUFSZ  = ABYTES + BBYTES;        // 32768
    __shared__ char lds[4 * BUFSZ];

    const int tid  = threadIdx.x;
    const int lane = tid & 63;
    const int w    = tid >> 6;           // 0..7
    const int wm   = w >> 2;             // 0..1
    const int wn   = w & 3;              // 0..3

    // PV: 8m x 4n grid, XCD owns 2m x 2n rect
    const int d  = blockIdx.x;
    const int g  = d & 7;
    const int k_ = d >> 3;
    const int by = (g >> 1) * 2 + (k_ & 1);
    const int bx = (g & 1) * 2 + (k_ >> 1);
    const int m0 = by * BM_;
    const int n0 = bx * BN;
    const size_t z = blockIdx.y;

    const u16* A0 = A0g + z * szA;
    const u16* A1 = A1g + z * szA;
    const u16* B  = Bg  + z * szB;
    float* C = Cg + z * szC;

    const int  lr   = lane & 15;
    const uint csel = (uint)((((lane >> 4) ^ ((lane >> 1) & 3)) * 16));
    const int  cstg = (((lane & 3) ^ ((lane >> 3) & 3)) * 8);
    const int  rstg = lane >> 2;

    const uint awoff = (uint)(wm * 8192 + lr * 64) + csel;
    const uint bwoff = (uint)(wn * (NBF * 1024) + lr * 64) + csel;

    f32x4_t acc[8][NBF];
#pragma unroll
    for (int m = 0; m < 8; ++m)
#pragma unroll
        for (int n = 0; n < NBF; ++n)
            acc[m][n] = (f32x4_t){0.f, 0.f, 0.f, 0.f};

    auto stA = [&](int t) {
        const u16* Ab = (t < NTILES / 2) ? A0 : A1;
        const int kc = (t & (NTILES / 2 - 1)) * BK_ + cstg;
        char* dst = lds + (t & 3) * BUFSZ + w * 2048;
        gload_lds16(&Ab[(size_t)(m0 + w * 32 + rstg) * lda + kc], dst);
        gload_lds16(&Ab[(size_t)(m0 + w * 32 + 16 + rstg) * lda + kc], dst + 1024);
    };
    auto stB = [&](int t) {
        const int kc = ((t * BK_) & bkmask) + cstg;
        char* dst = lds + (t & 3) * BUFSZ + ABYTES;
        gload_lds16(&B[(size_t)(n0 + w * 32 + rstg) * ldb + kc], dst + w * 2048);
        gload_lds16(&B[(size_t)(n0 + w * 32 + 16 + rstg) * ldb + kc], dst + w * 2048 + 1024);
    };

    stA(0); stB(0); stA(1); stB(1); stA(2); stB(2);
    asm volatile("s_waitcnt vmcnt(8)" ::: "memory");
    __builtin_amdgcn_s_barrier();

#define LDF(p) (*(const f16x8_t*)(p))

#define PHASE_A(T, DOSTAGE)                                                   \
    {                                                                         \
        const char* pA = lds + ((T) & 3) * BUFSZ + awoff;                     \
        const char* pB = lds + ((T) & 3) * BUFSZ + ABYTES + bwoff;            \
        f16x8_t a[4], b[NBF];                                                 \
        a[0] = LDF(pA);        a[1] = LDF(pA + 1024);                         \
        a[2] = LDF(pA + 2048); a[3] = LDF(pA + 3072);                         \
        b[0] = LDF(pB);        b[1] = LDF(pB + 1024);                         \
        b[2] = LDF(pB + 2048); b[3] = LDF(pB + 3072);                         \
        if (DOSTAGE) stA((T) + 3);                                            \
        __builtin_amdgcn_s_barrier();                                         \
        __builtin_amdgcn_s_setprio(1);                                        \
        _Pragma("unroll")                                                     \
        for (int mf = 0; mf < 4; ++mf)                                        \
            _Pragma("unroll")                                                 \
            for (int nf = 0; nf < NBF; ++nf)                                  \
                acc[mf][nf] = __builtin_amdgcn_mfma_f32_16x16x32_f16(         \
                    a[mf], b[nf], acc[mf][nf], 0, 0, 0);                      \
        __builtin_amdgcn_s_setprio(0);                                        \
        bsave[0] = b[0]; bsave[1] = b[1]; bsave[2] = b[2]; bsave[3] = b[3];   \
        __builtin_amdgcn_s_barrier();                                         \
    }

#define PHASE_B(T, DOSTAGE, VMASM)                                            \
    {                                                                         \
        const char* pA = lds + ((T) & 3) * BUFSZ + awoff;                     \
        f16x8_t a[4];                                                         \
        a[0] = LDF(pA + 4096); a[1] = LDF(pA + 5120);                         \
        a[2] = LDF(pA + 6144); a[3] = LDF(pA + 7168);                         \
        if (DOSTAGE) stB((T) + 3);                                            \
        __builtin_amdgcn_s_barrier();                                         \
        __builtin_amdgcn_s_setprio(1);                                        \
        _Pragma("unroll")                                                     \
        for (int mf = 0; mf < 4; ++mf)                                        \
            _Pragma("unroll")                                                 \
            for (int nf = 0; nf < NBF; ++nf)                                  \
                acc[4 + mf][nf] = __builtin_amdgcn_mfma_f32_16x16x32_f16(     \
                    a[mf], bsave[nf], acc[4 + mf][nf], 0, 0, 0);              \
        __builtin_amdgcn_s_setprio(0);                                        \
        VMASM;                                                                \
        __builtin_amdgcn_s_barrier();                                         \
    }

#define VMW asm volatile("s_waitcnt vmcnt(8)" ::: "memory")
#define VMH asm volatile("s_waitcnt vmcnt(4)" ::: "memory")
#define VM0 asm volatile("s_waitcnt vmcnt(0)" ::: "memory")
#define VMN do {} while (0)

    f16x8_t bsave[NBF];

    for (int t = 0; t < NTILES - 3; ++t) {
        PHASE_A(t, true);
        PHASE_B(t, true, VMW);
    }
    PHASE_A(NTILES - 3, false); PHASE_B(NTILES - 3, false, VMH);
    PHASE_A(NTILES - 2, false); PHASE_B(NTILES - 2, false, VM0);
    PHASE_A(NTILES - 1, false); PHASE_B(NTILES - 1, false, VMN);
#undef PHASE_A
#undef PHASE_B
#undef LDF

    const int cg = lane >> 4;
#pragma unroll
    for (int mf = 0; mf < 8; ++mf)
#pragma unroll
        for (int nf = 0; nf < NBF; ++nf) {
            const int row = m0 + wm * 128 + mf * 16 + cg * 4;
            const int col = n0 + wn * (NBF * 16) + nf * 16 + lr;
#pragma unroll
            for (int r = 0; r < 4; ++r)
                C[(size_t)(row + r) * ldc + col] = acc[mf][nf][r];
        }
}

// ---------- masked row softmax, z-batched: S fp32 -> P fp16 IN PLACE ----------
__global__ __launch_bounds__(256) void softmax_mask(
    float* __restrict__ S, const int* __restrict__ mask0)
{
    const int lane = threadIdx.x & 63;
    const int wave = threadIdx.x >> 6;
    const int row  = blockIdx.x * 4 + wave;
    const size_t zb = blockIdx.y;
    float* Sr = S + (zb * LQ_ + row) * (size_t)LK_;
    const int* mb = mask0 + zb * LK_;

    float4 s[8];
    float m = -INFINITY;
#pragma unroll
    for (int i = 0; i < 8; ++i) {
        int k = i * 256 + lane * 4;
        float4 v = *(const float4*)&Sr[k];
        int4 mk  = *(const int4*)&mb[k];
        v.x = mk.x ? v.x : NEG_INF;
        v.y = mk.y ? v.y : NEG_INF;
        v.z = mk.z ? v.z : NEG_INF;
        v.w = mk.w ? v.w : NEG_INF;
        s[i] = v;
        m = fmaxf(m, fmaxf(fmaxf(v.x, v.y), fmaxf(v.z, v.w)));
    }
#pragma unroll
    for (int off = 32; off > 0; off >>= 1)
        m = fmaxf(m, __shfl_xor(m, off, 64));
    float sum = 0.f;
#pragma unroll
    for (int i = 0; i < 8; ++i) {
        s[i].x = __expf(s[i].x - m); sum += s[i].x;
        s[i].y = __expf(s[i].y - m); sum += s[i].y;
        s[i].z = __expf(s[i].z - m); sum += s[i].z;
        s[i].w = __expf(s[i].w - m); sum += s[i].w;
    }
#pragma unroll
    for (int off = 32; off > 0; off >>= 1)
        sum += __shfl_xor(sum, off, 64);
    const float inv = 1.f / sum;
    u16* Pr = (u16*)Sr;
#pragma unroll
    for (int i = 0; i < 8; ++i) {
        int k = i * 256 + lane * 4;
        ushort4 o;
        o.x = f2h_bits(s[i].x * inv);
        o.y = f2h_bits(s[i].y * inv);
        o.z = f2h_bits(s[i].z * inv);
        o.w = f2h_bits(s[i].w * inv);
        *(ushort4*)&Pr[k] = o;
    }
}

// ---------- fallback (verified R1 fp32 kernel) ----------
__global__ __launch_bounds__(256, 2) void attn_fp32_flash(
    const float* __restrict__ hidden, const float* __restrict__ keys,
    const float* __restrict__ values, const int* __restrict__ mask,
    float* __restrict__ out)
{
    const int lane = threadIdx.x & 63;
    const int wave = threadIdx.x >> 6;
    const int blk  = blockIdx.x;
    const int b    = blk >> 7;
    const int q0   = (blk & 127) * 16 + wave * 4;
    float4 q[4][4]; float4 o[4][4]; float m[4], s[4];
    const float4* hp = (const float4*)(hidden + ((size_t)b * LQ_ + q0) * D_);
#pragma unroll
    for (int r = 0; r < 4; ++r) {
#pragma unroll
        for (int j = 0; j < 4; ++j) {
            q[r][j] = hp[r * 256 + j * 64 + lane];
            o[r][j] = make_float4(0.f, 0.f, 0.f, 0.f);
        }
        m[r] = -INFINITY; s[r] = 0.f;
    }
    const float4* kp = (const float4*)(keys   + (size_t)b * LK_ * D_);
    const float4* vp = (const float4*)(values + (size_t)b * LK_ * D_);
    const int*    mp = mask + b * LK_;
    for (int k = 0; k < LK_; ++k) {
        float4 kv[4];
#pragma unroll
        for (int j = 0; j < 4; ++j) kv[j] = kp[k * 256 + j * 64 + lane];
        float sc[4];
#pragma unroll
        for (int r = 0; r < 4; ++r) {
            float p = 0.f;
#pragma unroll
            for (int j = 0; j < 4; ++j)
                p += q[r][j].x * kv[j].x + q[r][j].y * kv[j].y +
                     q[r][j].z * kv[j].z + q[r][j].w * kv[j].w;
            sc[r] = p;
        }
#pragma unroll
        for (int r = 0; r < 4; ++r)
#pragma unroll
            for (int off = 32; off > 0; off >>= 1)
                sc[r] += __shfl_xor(sc[r], off, 64);
        const int mk = mp[k];
        float4 vv[4];
#pragma unroll
        for (int j = 0; j < 4; ++j) vv[j] = vp[k * 256 + j * 64 + lane];
#pragma unroll
        for (int r = 0; r < 4; ++r) {
            float score = mk ? sc[r] : NEG_INF;
            if (score > m[r]) {
                float scale = __expf(m[r] - score);
                m[r] = score; s[r] *= scale;
#pragma unroll
                for (int j = 0; j < 4; ++j) {
                    o[r][j].x *= scale; o[r][j].y *= scale;
                    o[r][j].z *= scale; o[r][j].w *= scale;
                }
            }
            float e = __expf(score - m[r]);
            s[r] += e;
#pragma unroll
            for (int j = 0; j < 4; ++j) {
                o[r][j].x += e * vv[j].x; o[r][j].y += e * vv[j].y;
                o[r][j].z += e * vv[j].z; o[r][j].w += e * vv[j].w;
            }
        }
    }
    float4* op = (float4*)(out + ((size_t)b * LQ_ + q0) * D_);
#pragma unroll
    for (int r = 0; r < 4; ++r) {
        float inv = 1.f / s[r];
#pragma unroll
        for (int j = 0; j < 4; ++j) {
            float4 t = o[r][j];
            t.x *= inv; t.y *= inv; t.z *= inv; t.w *= inv;
            op[r * 256 + j * 64 + lane] = t;
        }
    }
}

extern "C" void kernel_launch(void* const* d_in, const int* in_sizes, int n_in,
                              void* d_out, int out_size, void* d_ws, size_t ws_size,
                              hipStream_t stream) {
    const float* hidden = (const float*)d_in[0];
    const float* keys   = (const float*)d_in[1];
    const float* values = (const float*)d_in[2];
    const int*   mask   = (const int*)d_in[3];
    float* out = (float*)d_out;
    char* ws = (char*)d_ws;

    const size_t TEN = (size_t)LK_ * D_;          // 2M elems per batch tensor
    const size_t MB  = 1024ull * 1024;

    // per-batch footprint: Kh 4 + VT 4 + Qh 4 + S 16 (P in place) = 28 MiB
    int BG = 0;
    for (int g = 8; g >= 1; g >>= 1)
        if ((size_t)g * 28 * MB <= ws_size) { BG = g; break; }

    if (BG == 0) {
        attn_fp32_flash<<<1024, 256, 0, stream>>>(hidden, keys, values, mask, out);
        return;
    }

    const size_t SZ_BF = (size_t)BG * TEN * 2;            // BG*4 MiB per u16 tensor
    u16*   Kh = (u16*)(ws);
    u16*   VT = (u16*)(ws + SZ_BF);
    u16*   Qh = (u16*)(ws + 2 * SZ_BF);
    float* S  = (float*)(ws + 3 * SZ_BF);                 // BG*16 MiB

    const int n4 = BG * (int)(TEN / 4);

    for (int bg0 = 0; bg0 < B_; bg0 += BG) {
        const size_t off = (size_t)bg0 * TEN;
        // K and Q fp16 converts fused into one dispatch
        convert_f16_2<<<4096, 256, 0, stream>>>(
            (const float4*)(keys + off), (ushort4*)Kh,
            (const float4*)(hidden + off), (ushort4*)Qh, n4);
        transpose_convert<<<dim3(16, 32, BG), 256, 0, stream>>>(
            values + off, VT);

        // S = Qh * Kh^T — ring-2 (64 KiB), 2 blocks/CU co-resident
        gemm_qk2<<<dim3(64, BG), 512, 0, stream>>>(
            Qh, Kh, S, TEN, TEN, (size_t)LQ_ * LK_);

        // softmax, P written fp16 in place over the first half of each S row
        softmax_mask<<<dim3(LQ_ / 4, BG), 256, 0, stream>>>(
            S, mask + bg0 * LK_);

        // out = P * VT^T — 256x256 tile, ring-4; P rows at stride 4096 u16
        gemm8p<64><<<dim3(32, BG), 512, 0, stream>>>(
            (const u16*)S, (const u16*)S + 1024, VT, out + off,
            2 * LK_, LK_, D_, 2047,
            (size_t)LQ_ * 2 * LK_, TEN, (size_t)LQ_ * D_);
    }
}